// Round 3
// baseline (163.635 us; speedup 1.0000x reference)
//
#include <hip/hip_runtime.h>
#include <hip/hip_bf16.h>

#define D 96
#define CAP 32          // one 64-B slot line per node; deg>32 -> overflow list
#define OVF_MAX 65536
#define NTILE 128       // period-24 tiles: 16 fill + 8 gemm each
#define FILLB 2048      // = NTILE*16

typedef __attribute__((ext_vector_type(8))) short bf16x8;
typedef __attribute__((ext_vector_type(4))) float f32x4;
typedef unsigned u32x3 __attribute__((ext_vector_type(3), aligned(4)));

__device__ __forceinline__ short f2bf(float f)
{
    union { __hip_bfloat16 h; short s; } u;
    u.h = __float2bfloat16(f);
    return u.s;
}

__device__ __forceinline__ bf16x8 load_frag(const float* p)
{
    float4 lo = *(const float4*)p;
    float4 hi = *(const float4*)(p + 4);
    bf16x8 r;
    r[0] = f2bf(lo.x); r[1] = f2bf(lo.y); r[2] = f2bf(lo.z); r[3] = f2bf(lo.w);
    r[4] = f2bf(hi.x); r[5] = f2bf(hi.y); r[6] = f2bf(hi.z); r[7] = f2bf(hi.w);
    return r;
}

__device__ __forceinline__ float bf_lo(unsigned p) { return __uint_as_float(p << 16); }
__device__ __forceinline__ float bf_hi(unsigned p) { return __uint_as_float(p & 0xFFFF0000u); }

// ---------------------------------------------------------------------------
// K0: init — zero cnt[N+1] (replaces hipMemsetAsync dispatch) AND build the
// fragment-ordered bf16 W table wbf[36][64] (36 KB). Stream-ordered before
// the fused kernel, so gemm waves can read wbf with no barrier concerns.
// ---------------------------------------------------------------------------
__global__ __launch_bounds__(256) void init_kernel(
    const float* __restrict__ Wl, const float* __restrict__ Wr,
    __hip_bfloat16* __restrict__ wbf, int* __restrict__ cnt, int N)
{
    const int idx = blockIdx.x * 256 + threadIdx.x;
    if (idx <= N) cnt[idx] = 0;
    if (idx < 2304) {
        int mat = idx / 1152;                    // 0=Wl, 1=Wr
        int rem = idx - mat * 1152;
        int n  = rem / 12;                       // W row = output col (0..95)
        int k8 = rem - n * 12;                   // 8-float group along K
        const float* Wp = mat ? Wr : Wl;
        bf16x8 v = load_frag(Wp + (size_t)n * D + k8 * 8);
        int ct = n >> 4, m = n & 15, kt = k8 >> 2, quad = k8 & 3;
        ((bf16x8*)wbf)[(mat * 18 + ct * 3 + kt) * 64 + quad * 16 + m] = v;
    }
}

// ---------------------------------------------------------------------------
// K1 (fused): period-24 tiling — t=bid%24: t<16 -> fill, else gemm.
// R14 fill role: NO dst-range filter. Each fill block owns a contiguous
// ~391-edge chunk and processes every edge once (was: 8 blocks each scanning
// the chunk and keeping 1/8 -> 8x instruction inflation, 12% lane density on
// the atomic path). Device-scope atomics execute memory-side regardless of
// issuing XCD, so the XCD-pinned filter bought no atomic locality; counters
// (VALU 5.6%, HBM 22%) say fill is issue/latency-bound -> dense waves win.
// ---------------------------------------------------------------------------
__global__ __launch_bounds__(256) void fused_gf_kernel(
    const float* __restrict__ x, const int* __restrict__ src,
    const int* __restrict__ dst, const __hip_bfloat16* __restrict__ wbf,
    __hip_bfloat16* __restrict__ hl, float* __restrict__ hr,
    int* __restrict__ cnt, unsigned short* __restrict__ slot,
    int* __restrict__ ovf, int N, int E)
{
    const int bid = blockIdx.x;
    const int tile = bid / 24;
    const int t = bid - tile * 24;

    if (t < 16) {
        // ---- fill role: one edge chunk per block, all dst processed ----
        const int fid = tile * 16 + t;           // 0..2047
        const int CS = (E + FILLB - 1) / FILLB;  // 391
        const int base = fid * CS;
        int lim = E - base; if (lim > CS) lim = CS; if (lim < 0) lim = 0;
        for (int i = threadIdx.x; i < lim; i += 256) {
            int e = base + i;
            int d  = dst[e];
            int sv = src[e];
            int pos = atomicAdd(&cnt[d], 1);
            if (pos < CAP) {
                slot[(size_t)d * CAP + pos] = (unsigned short)sv;
            } else {
                int o = atomicAdd(&cnt[N], 1);
                if (o < OVF_MAX) { ovf[2 * o] = d; ovf[2 * o + 1] = sv; }
            }
        }
        return;
    }

    // ---- gemm role (MFMA layouts verified R4; wbf table path verified R13) ----
    const int gk = tile * 8 + (t - 16);          // 0..1023 (need 782)
    const int gwave = (gk * 256 + threadIdx.x) >> 6;
    const int nrt = N / 16;                      // 3125 (exact)
    if (gwave >= nrt) return;
    const int lane = threadIdx.x & 63;
    const int m = lane & 15, quad = lane >> 4;
    const int row = gwave * 16 + m;
    const bf16x8* wb = (const bf16x8*)wbf;

    bf16x8 a[3];
    #pragma unroll
    for (int kt = 0; kt < 3; ++kt)
        a[kt] = load_frag(x + (size_t)row * D + kt * 32 + quad * 8);

    const int orow = gwave * 16 + quad * 4;
    #pragma unroll
    for (int ct = 0; ct < 6; ++ct) {
        f32x4 accl = {0.f, 0.f, 0.f, 0.f};
        f32x4 accr = {0.f, 0.f, 0.f, 0.f};
        #pragma unroll
        for (int kt = 0; kt < 3; ++kt)
            accl = __builtin_amdgcn_mfma_f32_16x16x32_bf16(
                a[kt], wb[(ct * 3 + kt) * 64 + lane], accl, 0, 0, 0);
        #pragma unroll
        for (int kt = 0; kt < 3; ++kt)
            accr = __builtin_amdgcn_mfma_f32_16x16x32_bf16(
                a[kt], wb[(18 + ct * 3 + kt) * 64 + lane], accr, 0, 0, 0);
        int col = ct * 16 + m;
        int sl = col / 24, c = col - sl * 24;    // slice, col-in-slice (pad to 32)
        #pragma unroll
        for (int r = 0; r < 4; ++r) {
            int node = orow + r;
            hl[((size_t)sl * N + node) * 32 + c] = __float2bfloat16(accl[r]);
            hr[(size_t)node * D + col] = accr[r];
        }
    }
}

// ---------------------------------------------------------------------------
// K2: gather-mean + bias + relu (unchanged, R12 structure: 4 nodes/wave,
// slice pinned to XCD pair for L2 residency of one 3.2-MB hl slice).
// ---------------------------------------------------------------------------
__global__ __launch_bounds__(256) void agg_kernel(
    const __hip_bfloat16* __restrict__ hl, const int* __restrict__ cnt,
    const unsigned short* __restrict__ slot, const int* __restrict__ ovf,
    const float* __restrict__ bl, float* __restrict__ out, int N)
{
    const int lane = threadIdx.x & 63;
    const int wv = threadIdx.x >> 6;
    const int xcd = blockIdx.x & 7;
    const int s  = xcd >> 1;                     // slice 0..3
    const int sb = ((blockIdx.x >> 3) << 1) | (xcd & 1);  // node group 0..3124
    if (sb >= 3125) return;                      // grid = 12504, tail guard
    const int n0 = sb * 16 + wv * 4;             // 4 nodes per wave
    const int nn = lane >> 4;                    // node in quad
    const int e4 = (lane >> 2) & 3;              // edge-parallel
    const int r  = lane & 3;                     // 12-B quarter of 48-B row
    const int n  = n0 + nn;

    const int deg = cnt[n];                      // broadcast within 16 lanes
    const int dcm = min(deg, CAP);
    const unsigned* slotD = (const unsigned*)slot;
    unsigned sid = slotD[(size_t)n0 * 16 + lane];   // lane = nn*16 + dword
    int um = dcm;
    um = max(um, __shfl_xor(um, 16));
    um = max(um, __shfl_xor(um, 32));

    const unsigned short* hs = (const unsigned short*)hl + (size_t)s * N * 32;
    float a0 = 0.f, a1 = 0.f, a2 = 0.f, a3 = 0.f, a4 = 0.f, a5 = 0.f;
    #pragma unroll 2
    for (int j = 0; j < um; j += 4) {
        int idx = j + e4;
        unsigned dw = __shfl(sid, nn * 16 + (idx >> 1));
        bool act = idx < dcm;
        int nb = act ? ((idx & 1) ? (int)(dw >> 16) : (int)(dw & 0xFFFFu)) : 0;
        u32x3 p = *(const u32x3*)((const char*)hs + (size_t)nb * 64 + r * 12);
        float mk = act ? 1.f : 0.f;
        a0 += mk * bf_lo(p.x); a1 += mk * bf_hi(p.x);
        a2 += mk * bf_lo(p.y); a3 += mk * bf_hi(p.y);
        a4 += mk * bf_lo(p.z); a5 += mk * bf_hi(p.z);
    }
    #pragma unroll
    for (int off = 4; off <= 8; off <<= 1) {
        a0 += __shfl_xor(a0, off); a1 += __shfl_xor(a1, off);
        a2 += __shfl_xor(a2, off); a3 += __shfl_xor(a3, off);
        a4 += __shfl_xor(a4, off); a5 += __shfl_xor(a5, off);
    }
    if (e4 == 0) {                               // 16 lanes: 4 nodes x 4 quarters
        int ovfn = min(cnt[N], OVF_MAX);
        if (ovfn) {                              // deg>32 tail (rare)
            for (int k = 0; k < ovfn; ++k) {
                if (ovf[2 * k] == n) {
                    int nb = ovf[2 * k + 1];
                    u32x3 p = *(const u32x3*)((const char*)hs + (size_t)nb * 64 + r * 12);
                    a0 += bf_lo(p.x); a1 += bf_hi(p.x);
                    a2 += bf_lo(p.y); a3 += bf_hi(p.y);
                    a4 += bf_lo(p.z); a5 += bf_hi(p.z);
                }
            }
        }
        const int o = s * 24 + r * 6;
        float inv = 1.0f / fmaxf((float)deg, 1.0f);
        float* op = out + (size_t)n * D + o;
        float2 u0 = *(const float2*)op;
        float2 u1 = *(const float2*)(op + 2);
        float2 u2 = *(const float2*)(op + 4);
        u0.x = fmaxf(a0 * inv + bl[o]     + u0.x, 0.f);
        u0.y = fmaxf(a1 * inv + bl[o + 1] + u0.y, 0.f);
        u1.x = fmaxf(a2 * inv + bl[o + 2] + u1.x, 0.f);
        u1.y = fmaxf(a3 * inv + bl[o + 3] + u1.y, 0.f);
        u2.x = fmaxf(a4 * inv + bl[o + 4] + u2.x, 0.f);
        u2.y = fmaxf(a5 * inv + bl[o + 5] + u2.y, 0.f);
        *(float2*)op       = u0;
        *(float2*)(op + 2) = u1;
        *(float2*)(op + 4) = u2;
    }
}

extern "C" void kernel_launch(void* const* d_in, const int* in_sizes, int n_in,
                              void* d_out, int out_size, void* d_ws, size_t ws_size,
                              hipStream_t stream)
{
    const float* x  = (const float*)d_in[0];
    const int*   ei = (const int*)d_in[1];   // [2, E]: src row then dst row
    const float* Wl = (const float*)d_in[2];
    const float* bl = (const float*)d_in[3];
    const float* Wr = (const float*)d_in[4];
    float* out = (float*)d_out;

    const int N = in_sizes[0] / D;   // 50000
    const int E = in_sizes[1] / 2;   // 800000
    const int* src = ei;
    const int* dst = ei + E;

    // ws: wbf[36*64*16B] frag-ordered bf16 W (36,864 B), then hl[4*N*32] bf16
    // (12.8 MB, 64-B rows), slot[N*CAP] u16, cnt[N+1], ovf
    __hip_bfloat16* wbf = (__hip_bfloat16*)d_ws;
    __hip_bfloat16* hl = (__hip_bfloat16*)((char*)d_ws + 36864);
    unsigned short* slot = (unsigned short*)(hl + (size_t)4 * N * 32);
    int* cnt = (int*)(slot + (size_t)N * CAP);
    int* ovf = cnt + (N + 1);

    // K0 replaces the cnt memset AND builds wbf (196*256 = 50176 threads)
    init_kernel<<<196, 256, 0, stream>>>(Wl, Wr, wbf, cnt, N);

    fused_gf_kernel<<<NTILE * 24, 256, 0, stream>>>(
        x, src, dst, wbf, hl, out, cnt, slot, ovf, N, E);

    // 3125 node-groups x 4 slices -> 12504 blocks (sb guard trims tail)
    agg_kernel<<<12504, 256, 0, stream>>>(hl, cnt, slot, ovf, bl, out, N);
}

// Round 4
// 152.300 us; speedup vs baseline: 1.0744x; 1.0744x over previous
//
#include <hip/hip_runtime.h>
#include <hip/hip_bf16.h>

#define D 96
#define CAP 32          // one 64-B slot line per node; deg>32 -> overflow list
#define OVF_MAX 65536
#define NB1 256         // edge-chunk blocks in P1/P2 (E/256 = 3125 edges each)
#define BUKSHIFT 8      // bucket = dst >> 8 : 256 nodes per bucket
#define CAPB 8192       // bucket edge capacity (mean 4096, 2x headroom)

typedef __attribute__((ext_vector_type(8))) short bf16x8;
typedef __attribute__((ext_vector_type(4))) float f32x4;
typedef unsigned u32x3 __attribute__((ext_vector_type(3), aligned(4)));

__device__ __forceinline__ short f2bf(float f)
{
    union { __hip_bfloat16 h; short s; } u;
    u.h = __float2bfloat16(f);
    return u.s;
}

__device__ __forceinline__ bf16x8 load_frag(const float* p)
{
    float4 lo = *(const float4*)p;
    float4 hi = *(const float4*)(p + 4);
    bf16x8 r;
    r[0] = f2bf(lo.x); r[1] = f2bf(lo.y); r[2] = f2bf(lo.z); r[3] = f2bf(lo.w);
    r[4] = f2bf(hi.x); r[5] = f2bf(hi.y); r[6] = f2bf(hi.z); r[7] = f2bf(hi.w);
    return r;
}

__device__ __forceinline__ float bf_lo(unsigned p) { return __uint_as_float(p << 16); }
__device__ __forceinline__ float bf_hi(unsigned p) { return __uint_as_float(p & 0xFFFF0000u); }

// ---------------------------------------------------------------------------
// K0: init — build the fragment-ordered bf16 W table wbf[36][64] (36 KB) and
// zero the overflow counter cnt[N]. cnt[0..N-1] needs NO zeroing: P3 writes
// every node's count. Grid 9x256 = 2304 threads.
// ---------------------------------------------------------------------------
__global__ __launch_bounds__(256) void init_kernel(
    const float* __restrict__ Wl, const float* __restrict__ Wr,
    __hip_bfloat16* __restrict__ wbf, int* __restrict__ cnt, int N)
{
    const int idx = blockIdx.x * 256 + threadIdx.x;
    if (idx == 0) cnt[N] = 0;
    if (idx < 2304) {
        int mat = idx / 1152;                    // 0=Wl, 1=Wr
        int rem = idx - mat * 1152;
        int n  = rem / 12;                       // W row = output col (0..95)
        int k8 = rem - n * 12;                   // 8-float group along K
        const float* Wp = mat ? Wr : Wl;
        bf16x8 v = load_frag(Wp + (size_t)n * D + k8 * 8);
        int ct = n >> 4, m = n & 15, kt = k8 >> 2, quad = k8 & 3;
        ((bf16x8*)wbf)[(mat * 18 + ct * 3 + kt) * 64 + quad * 16 + m] = v;
    }
}

// ---------------------------------------------------------------------------
// P1: per-(block,bucket) histogram via LDS (no global atomics).
// hist[blk*nbuk + bu], coalesced writeout.
// ---------------------------------------------------------------------------
__global__ __launch_bounds__(256) void p1_hist(
    const int* __restrict__ dst, int* __restrict__ hist, int nbuk, int E)
{
    __shared__ int h[256];
    for (int i = threadIdx.x; i < nbuk; i += 256) h[i] = 0;
    __syncthreads();
    const int CS = (E + NB1 - 1) / NB1;          // 3125
    const int base = blockIdx.x * CS;
    int lim = E - base; if (lim > CS) lim = CS; if (lim < 0) lim = 0;
    for (int i = threadIdx.x; i < lim; i += 256)
        atomicAdd(&h[dst[base + i] >> BUKSHIFT], 1);
    __syncthreads();
    for (int i = threadIdx.x; i < nbuk; i += 256)
        hist[blockIdx.x * nbuk + i] = h[i];
}

// ---------------------------------------------------------------------------
// Kpre: per bucket (one block each), exclusive scan of the 256 block-counts
// -> ofs[blk][bu] = bu*CAPB + excl_prefix; tot[bu] = bucket total.
// Fixed bucket bases (bu*CAPB) remove all cross-bucket coupling.
// ---------------------------------------------------------------------------
__global__ __launch_bounds__(256) void kpre(
    const int* __restrict__ hist, int* __restrict__ ofs,
    int* __restrict__ tot, int nbuk)
{
    __shared__ int sc[256];
    const int bu = blockIdx.x, t = threadIdx.x;
    int v = hist[t * nbuk + bu];
    sc[t] = v;
    __syncthreads();
    #pragma unroll
    for (int off = 1; off < 256; off <<= 1) {    // Hillis-Steele inclusive
        int x = (t >= off) ? sc[t - off] : 0;
        __syncthreads();
        sc[t] += x;
        __syncthreads();
    }
    ofs[t * nbuk + bu] = bu * CAPB + (sc[t] - v);
    if (t == 255) tot[bu] = sc[t];
}

// ---------------------------------------------------------------------------
// P2 (fused): bid<NB1 -> bucket scatter (LDS-offset, NO global atomics:
// packed src|dloc<<16 u32 written into per-(block,bucket) contiguous runs
// ~16 edges -> near-full-line writes). bid>=NB1 -> gemm role (unchanged,
// MFMA layouts verified R4, wbf table verified R13); gemm (~10us) hides
// under the scatter pass in the same dispatch.
// ---------------------------------------------------------------------------
__global__ __launch_bounds__(256) void p2_gemm(
    const int* __restrict__ src, const int* __restrict__ dst,
    const int* __restrict__ ofs, unsigned* __restrict__ ebuf,
    const float* __restrict__ x, const __hip_bfloat16* __restrict__ wbf,
    __hip_bfloat16* __restrict__ hl, float* __restrict__ hr,
    int nbuk, int N, int E)
{
    if (blockIdx.x < NB1) {
        __shared__ int mo[256];
        for (int i = threadIdx.x; i < nbuk; i += 256)
            mo[i] = ofs[blockIdx.x * nbuk + i];
        __syncthreads();
        const int CS = (E + NB1 - 1) / NB1;
        const int base = blockIdx.x * CS;
        int lim = E - base; if (lim > CS) lim = CS; if (lim < 0) lim = 0;
        for (int i = threadIdx.x; i < lim; i += 256) {
            int e = base + i;
            int d = dst[e], s = src[e];
            int bu = d >> BUKSHIFT;
            int g = atomicAdd(&mo[bu], 1);       // LDS atomic
            if (g < (bu + 1) * CAPB)             // capacity guard (astronomic)
                ebuf[g] = (unsigned)s | ((unsigned)(d & 255) << 16);
        }
        return;
    }

    // ---- gemm role ----
    const int gk = blockIdx.x - NB1;
    const int gwave = (gk * 256 + threadIdx.x) >> 6;
    const int nrt = N / 16;                      // 3125 (exact)
    if (gwave >= nrt) return;
    const int lane = threadIdx.x & 63;
    const int m = lane & 15, quad = lane >> 4;
    const int row = gwave * 16 + m;
    const bf16x8* wb = (const bf16x8*)wbf;

    bf16x8 a[3];
    #pragma unroll
    for (int kt = 0; kt < 3; ++kt)
        a[kt] = load_frag(x + (size_t)row * D + kt * 32 + quad * 8);

    const int orow = gwave * 16 + quad * 4;
    #pragma unroll
    for (int ct = 0; ct < 6; ++ct) {
        f32x4 accl = {0.f, 0.f, 0.f, 0.f};
        f32x4 accr = {0.f, 0.f, 0.f, 0.f};
        #pragma unroll
        for (int kt = 0; kt < 3; ++kt)
            accl = __builtin_amdgcn_mfma_f32_16x16x32_bf16(
                a[kt], wb[(ct * 3 + kt) * 64 + lane], accl, 0, 0, 0);
        #pragma unroll
        for (int kt = 0; kt < 3; ++kt)
            accr = __builtin_amdgcn_mfma_f32_16x16x32_bf16(
                a[kt], wb[(18 + ct * 3 + kt) * 64 + lane], accr, 0, 0, 0);
        int col = ct * 16 + m;
        int sl = col / 24, c = col - sl * 24;    // slice, col-in-slice (pad to 32)
        #pragma unroll
        for (int r = 0; r < 4; ++r) {
            int node = orow + r;
            hl[((size_t)sl * N + node) * 32 + c] = __float2bfloat16(accl[r]);
            hr[(size_t)node * D + col] = accr[r];
        }
    }
}

// ---------------------------------------------------------------------------
// P3: per bucket, build slot lists + counts ENTIRELY in LDS (LDS atomics on
// 256 counters), then write 16 KB slot + 1 KB cnt per bucket fully coalesced.
// Only deg>32 overflow edges (~0-5 total) touch a global atomic.
// ---------------------------------------------------------------------------
__global__ __launch_bounds__(256) void p3_build(
    const unsigned* __restrict__ ebuf, const int* __restrict__ tot,
    int* __restrict__ cnt, unsigned short* __restrict__ slot,
    int* __restrict__ ovf, int N)
{
    __shared__ int cl[256];
    __shared__ unsigned short sl[256 * CAP];     // 16 KB
    const int bu = blockIdx.x, t = threadIdx.x;
    cl[t] = 0;
    __syncthreads();
    const int n = tot[bu];
    const unsigned* eb = ebuf + (size_t)bu * CAPB;
    for (int i = t; i < n; i += 256) {
        unsigned e = eb[i];
        int dl = e >> 16, s = e & 0xFFFFu;
        int pos = atomicAdd(&cl[dl], 1);         // LDS atomic
        if (pos < CAP) {
            sl[dl * CAP + pos] = (unsigned short)s;
        } else {
            int o = atomicAdd(&cnt[N], 1);
            if (o < OVF_MAX) { ovf[2 * o] = (bu << BUKSHIFT) + dl; ovf[2 * o + 1] = s; }
        }
    }
    __syncthreads();
    const int node = (bu << BUKSHIFT) + t;
    if (node < N) cnt[node] = cl[t];
    const unsigned* slD = (const unsigned*)sl;
    unsigned* sg = (unsigned*)slot + (size_t)bu * 256 * 16;
    #pragma unroll
    for (int k = 0; k < 16; ++k) {               // 4096 dwords, coalesced
        int idx = k * 256 + t;
        if (((bu << BUKSHIFT) + (idx >> 4)) < N) sg[idx] = slD[idx];
    }
}

// ---------------------------------------------------------------------------
// K2: gather-mean + bias + relu (unchanged, R12 structure: 4 nodes/wave,
// slice pinned to XCD pair for L2 residency of one 3.2-MB hl slice).
// ---------------------------------------------------------------------------
__global__ __launch_bounds__(256) void agg_kernel(
    const __hip_bfloat16* __restrict__ hl, const int* __restrict__ cnt,
    const unsigned short* __restrict__ slot, const int* __restrict__ ovf,
    const float* __restrict__ bl, float* __restrict__ out, int N)
{
    const int lane = threadIdx.x & 63;
    const int wv = threadIdx.x >> 6;
    const int xcd = blockIdx.x & 7;
    const int s  = xcd >> 1;                     // slice 0..3
    const int sb = ((blockIdx.x >> 3) << 1) | (xcd & 1);  // node group 0..3124
    if (sb >= 3125) return;                      // grid = 12504, tail guard
    const int n0 = sb * 16 + wv * 4;             // 4 nodes per wave
    const int nn = lane >> 4;                    // node in quad
    const int e4 = (lane >> 2) & 3;              // edge-parallel
    const int r  = lane & 3;                     // 12-B quarter of 48-B row
    const int n  = n0 + nn;

    const int deg = cnt[n];                      // broadcast within 16 lanes
    const int dcm = min(deg, CAP);
    const unsigned* slotD = (const unsigned*)slot;
    unsigned sid = slotD[(size_t)n0 * 16 + lane];   // lane = nn*16 + dword
    int um = dcm;
    um = max(um, __shfl_xor(um, 16));
    um = max(um, __shfl_xor(um, 32));

    const unsigned short* hs = (const unsigned short*)hl + (size_t)s * N * 32;
    float a0 = 0.f, a1 = 0.f, a2 = 0.f, a3 = 0.f, a4 = 0.f, a5 = 0.f;
    #pragma unroll 2
    for (int j = 0; j < um; j += 4) {
        int idx = j + e4;
        unsigned dw = __shfl(sid, nn * 16 + (idx >> 1));
        bool act = idx < dcm;
        int nb = act ? ((idx & 1) ? (int)(dw >> 16) : (int)(dw & 0xFFFFu)) : 0;
        u32x3 p = *(const u32x3*)((const char*)hs + (size_t)nb * 64 + r * 12);
        float mk = act ? 1.f : 0.f;
        a0 += mk * bf_lo(p.x); a1 += mk * bf_hi(p.x);
        a2 += mk * bf_lo(p.y); a3 += mk * bf_hi(p.y);
        a4 += mk * bf_lo(p.z); a5 += mk * bf_hi(p.z);
    }
    #pragma unroll
    for (int off = 4; off <= 8; off <<= 1) {
        a0 += __shfl_xor(a0, off); a1 += __shfl_xor(a1, off);
        a2 += __shfl_xor(a2, off); a3 += __shfl_xor(a3, off);
        a4 += __shfl_xor(a4, off); a5 += __shfl_xor(a5, off);
    }
    if (e4 == 0) {                               // 16 lanes: 4 nodes x 4 quarters
        int ovfn = min(cnt[N], OVF_MAX);
        if (ovfn) {                              // deg>32 tail (rare)
            for (int k = 0; k < ovfn; ++k) {
                if (ovf[2 * k] == n) {
                    int nb = ovf[2 * k + 1];
                    u32x3 p = *(const u32x3*)((const char*)hs + (size_t)nb * 64 + r * 12);
                    a0 += bf_lo(p.x); a1 += bf_hi(p.x);
                    a2 += bf_lo(p.y); a3 += bf_hi(p.y);
                    a4 += bf_lo(p.z); a5 += bf_hi(p.z);
                }
            }
        }
        const int o = s * 24 + r * 6;
        float inv = 1.0f / fmaxf((float)deg, 1.0f);
        float* op = out + (size_t)n * D + o;
        float2 u0 = *(const float2*)op;
        float2 u1 = *(const float2*)(op + 2);
        float2 u2 = *(const float2*)(op + 4);
        u0.x = fmaxf(a0 * inv + bl[o]     + u0.x, 0.f);
        u0.y = fmaxf(a1 * inv + bl[o + 1] + u0.y, 0.f);
        u1.x = fmaxf(a2 * inv + bl[o + 2] + u1.x, 0.f);
        u1.y = fmaxf(a3 * inv + bl[o + 3] + u1.y, 0.f);
        u2.x = fmaxf(a4 * inv + bl[o + 4] + u2.x, 0.f);
        u2.y = fmaxf(a5 * inv + bl[o + 5] + u2.y, 0.f);
        *(float2*)op       = u0;
        *(float2*)(op + 2) = u1;
        *(float2*)(op + 4) = u2;
    }
}

extern "C" void kernel_launch(void* const* d_in, const int* in_sizes, int n_in,
                              void* d_out, int out_size, void* d_ws, size_t ws_size,
                              hipStream_t stream)
{
    const float* x  = (const float*)d_in[0];
    const int*   ei = (const int*)d_in[1];   // [2, E]: src row then dst row
    const float* Wl = (const float*)d_in[2];
    const float* bl = (const float*)d_in[3];
    const float* Wr = (const float*)d_in[4];
    float* out = (float*)d_out;

    const int N = in_sizes[0] / D;   // 50000
    const int E = in_sizes[1] / 2;   // 800000
    const int* src = ei;
    const int* dst = ei + E;
    const int nbuk = (N + 255) >> BUKSHIFT;      // 196

    // ws layout (all 256-B aligned):
    //   wbf   36,864 B  frag-ordered bf16 W
    //   hl    4*N*32*2  = 12.8 MB (64-B slice rows)
    //   slot  N*CAP*2   = 3.2 MB
    //   cnt   (N+1)*4
    //   ovf   2*OVF_MAX*4
    //   hist  NB1*nbuk*4, ofs NB1*nbuk*4, tot nbuk*4
    //   ebuf  nbuk*CAPB*4 = 6.4 MB
    char* p = (char*)d_ws;
    __hip_bfloat16* wbf = (__hip_bfloat16*)p;          p += 36864;
    __hip_bfloat16* hl  = (__hip_bfloat16*)p;          p += (size_t)4 * N * 32 * 2;
    unsigned short* slot = (unsigned short*)p;         p += (size_t)N * CAP * 2;
    int* cnt = (int*)p;                                p += ((size_t)(N + 1) * 4 + 255) / 256 * 256;
    int* ovf = (int*)p;                                p += (size_t)2 * OVF_MAX * 4;
    int* hist = (int*)p;                               p += (size_t)NB1 * nbuk * 4;
    int* ofs = (int*)p;                                p += (size_t)NB1 * nbuk * 4;
    int* tot = (int*)p;                                p += ((size_t)nbuk * 4 + 255) / 256 * 256;
    unsigned* ebuf = (unsigned*)p;

    init_kernel<<<9, 256, 0, stream>>>(Wl, Wr, wbf, cnt, N);
    p1_hist<<<NB1, 256, 0, stream>>>(dst, hist, nbuk, E);
    kpre<<<nbuk, 256, 0, stream>>>(hist, ofs, tot, nbuk);

    const int nrt = N / 16;                      // 3125
    const int gemmb = (nrt + 3) / 4;             // 782
    p2_gemm<<<NB1 + gemmb, 256, 0, stream>>>(
        src, dst, ofs, ebuf, x, wbf, hl, out, nbuk, N, E);

    p3_build<<<nbuk, 256, 0, stream>>>(ebuf, tot, cnt, slot, ovf, N);

    // 3125 node-groups x 4 slices -> 12504 blocks (sb guard trims tail)
    agg_kernel<<<12504, 256, 0, stream>>>(hl, cnt, slot, ovf, bl, out, N);
}